// Round 1
// baseline (1032.206 us; speedup 1.0000x reference)
//
#include <hip/hip_runtime.h>
#include <hip/hip_bf16.h>
#include <math.h>

#define H 128
#define TILE 64
#define XB_STRIDE 136   // bf16 elems per LDS row: 272B -> 2-way bank aliasing (free)
#define PB_STRIDE 68    // f32 elems per pbuf row: 272B -> b128 reads hit the 8-phase minimum

typedef __attribute__((ext_vector_type(8))) short bf16x8;
typedef __attribute__((ext_vector_type(4))) float f32x4;

__device__ __forceinline__ short f2bf(float f) {
  union { float f; unsigned u; } v; v.f = f;
  unsigned r = v.u + 0x7fffu + ((v.u >> 16) & 1u);  // round-to-nearest-even
  return (short)(r >> 16);
}

// ---- K0: W1 (fp32, [k][n]) -> W1T bf16 [n][k], so B-frags are contiguous 16B ----
__global__ void prep_kernel(const float* __restrict__ w1, short* __restrict__ w1t) {
  int i = blockIdx.x * blockDim.x + threadIdx.x;   // 0 .. H*H-1
  if (i >= H * H) return;
  int k = i >> 7, n = i & (H - 1);
  w1t[n * H + k] = f2bf(w1[k * H + n]);
}

// ---- K1: segment boundaries from sorted batch_index ----
__global__ void bounds_kernel(const int* __restrict__ bi, int* __restrict__ seg_start,
                              int N, int B) {
  int n = blockIdx.x * blockDim.x + threadIdx.x;
  if (n >= N) return;
  int cur = bi[n];
  int prev = (n == 0) ? -1 : bi[n - 1];
  for (int g = prev + 1; g <= cur; ++g) seg_start[g] = n;
  if (n == N - 1) {
    for (int g = cur + 1; g <= B; ++g) seg_start[g] = N;
  }
}

// ---- K2: fused per-graph readout. x tile lives in REGISTERS (pool) + bf16 LDS (MFMA).
//      Softmax weights computed ONCE PER ROW; per-element scan is a single fma. ----
__global__ __launch_bounds__(256, 4) void fused_kernel(
    const float* __restrict__ x, const short* __restrict__ w1t,
    const float* __restrict__ b1, const float* __restrict__ w2,
    const float* __restrict__ b2, const int* __restrict__ seg_start,
    float* __restrict__ out)
{
  __shared__ __align__(16) short xb[TILE * XB_STRIDE];    // 17.4 KB bf16 tile (MFMA A)
  __shared__ __align__(16) float pbuf[TILE * PB_STRIDE];  // 17.4 KB gate partials; reused as merge buf
  __shared__ float w_lds[TILE];                           // per-row softmax weights
  __shared__ float bc2[2];                                // {m_new, tile_l} broadcast

  const int g = blockIdx.x;
  const int s = seg_start[g];
  const int e = seg_start[g + 1];
  const int R = e - s;

  const int tid  = threadIdx.x;
  const int w    = tid >> 6;       // wave 0..3 -> cols [32w, 32w+32)
  const int lane = tid & 63;
  const int l15  = lane & 15;
  const int q    = lane >> 4;

  // staging/pool identity: cols [c4, c4+4), rows rb + 8i
  const int c4 = (tid & 31) * 4;
  const int rb = tid >> 5;

  float4 sum4 = make_float4(0.f, 0.f, 0.f, 0.f);
  float4 mx4  = make_float4(-INFINITY, -INFINITY, -INFINITY, -INFINITY);
  float4 av4  = make_float4(0.f, 0.f, 0.f, 0.f);
  float m_run = -INFINITY, l_run = 0.f;

  const float b2v  = b2[0];
  const int   c0   = 32 * w + l15, c1 = c0 + 16;
  const float w2c0 = w2[c0], w2c1 = w2[c1];
  const float b1c0 = b1[c0], b1c1 = b1[c1];

  for (int t0 = 0; t0 < R; t0 += TILE) {
    const int Rt    = min(TILE, R - t0);
    const int mtMax = (Rt + 15) >> 4;    // skip all-OOB M-subtiles on tail tiles

    // ---- stage: global -> regs (fp32, pool) + LDS (bf16, MFMA A); fold in sum/max ----
    float4 xr[8];
#pragma unroll
    for (int i = 0; i < 8; ++i) {
      const int row = rb + 8 * i;
      const bool valid = row < Rt;
      float4 v = make_float4(0.f, 0.f, 0.f, 0.f);
      if (valid) v = *(const float4*)(x + (size_t)(s + t0 + row) * H + c4);
      xr[i] = v;
      sum4.x += v.x; sum4.y += v.y; sum4.z += v.z; sum4.w += v.w;
      if (valid) {
        mx4.x = fmaxf(mx4.x, v.x); mx4.y = fmaxf(mx4.y, v.y);
        mx4.z = fmaxf(mx4.z, v.z); mx4.w = fmaxf(mx4.w, v.w);
      }
      short4 sv = make_short4(f2bf(v.x), f2bf(v.y), f2bf(v.z), f2bf(v.w));
      *(short4*)(&xb[row * XB_STRIDE + c4]) = sv;   // zeros for OOB rows (clean A-frags)
    }
    __syncthreads();   // sync1: xb ready

    // ---- gate GEMM: (up to) 64x128 @ 128x128, bf16 MFMA ----
    f32x4 acc[4][2] = {};
#pragma unroll
    for (int kc = 0; kc < H; kc += 32) {
      bf16x8 a[4], b[2];
#pragma unroll
      for (int mt = 0; mt < 4; ++mt)
        if (mt < mtMax)
          a[mt] = *(const bf16x8*)(&xb[(16 * mt + l15) * XB_STRIDE + kc + 8 * q]);
#pragma unroll
      for (int nt = 0; nt < 2; ++nt) {
        int n = 32 * w + 16 * nt + l15;
        b[nt] = *(const bf16x8*)(w1t + n * H + kc + 8 * q);
      }
#pragma unroll
      for (int mt = 0; mt < 4; ++mt)
        if (mt < mtMax)
#pragma unroll
          for (int nt = 0; nt < 2; ++nt)
            acc[mt][nt] = __builtin_amdgcn_mfma_f32_16x16x32_bf16(a[mt], b[nt], acc[mt][nt], 0, 0, 0);
    }

    // ---- epilogue: silu(h)*W2 per (row, col-pair) -> pbuf[row][slot], no shfl/atomics ----
#pragma unroll
    for (int mt = 0; mt < 4; ++mt) {
      if (mt < mtMax) {
#pragma unroll
        for (int r = 0; r < 4; ++r) {
          float h0 = acc[mt][0][r] + b1c0;
          float h1 = acc[mt][1][r] + b1c1;
          float s0 = h0 / (1.0f + __expf(-h0));
          float s1 = h1 / (1.0f + __expf(-h1));
          pbuf[(16 * mt + 4 * q + r) * PB_STRIDE + 16 * w + l15] = s0 * w2c0 + s1 * w2c1;
        }
      }
    }
    __syncthreads();   // sync2: pbuf ready

    // ---- wave0: per-row gate, tile max, per-row exp weights, tile denom ----
    if (tid < 64) {
      const int row = tid;
      float4 t4 = make_float4(0.f, 0.f, 0.f, 0.f);
#pragma unroll
      for (int j = 0; j < 16; ++j) {
        float4 pv = *(const float4*)(&pbuf[row * PB_STRIDE + 4 * j]);
        t4.x += pv.x; t4.y += pv.y; t4.z += pv.z; t4.w += pv.w;
      }
      const float gate = (t4.x + t4.y) + (t4.z + t4.w) + b2v;
      const bool valid = row < Rt;
      float gm = valid ? gate : -INFINITY;    // mask stale/garbage rows (incl. NaN-safe)
#pragma unroll
      for (int m = 1; m < 64; m <<= 1) gm = fmaxf(gm, __shfl_xor(gm, m));
      const float m_new = fmaxf(m_run, gm);   // m_run identical on every thread
      const float wv = valid ? __expf(gate - m_new) : 0.f;
      w_lds[row] = wv;
      float tl = wv;
#pragma unroll
      for (int m = 1; m < 64; m <<= 1) tl += __shfl_xor(tl, m);
      if (tid == 0) { bc2[0] = m_new; bc2[1] = tl; }
    }
    __syncthreads();   // sync3: w_lds/bc2 ready

    // ---- attn numerator update: 1 fma per element, weights broadcast from LDS ----
    const float m_new = bc2[0];
    const float tl    = bc2[1];
    const float corr  = __expf(m_run - m_new);   // first tile: exp(-inf)=0
    m_run = m_new;
    l_run = l_run * corr + tl;
    av4.x *= corr; av4.y *= corr; av4.z *= corr; av4.w *= corr;
#pragma unroll
    for (int i = 0; i < 8; ++i) {
      const float wv = w_lds[rb + 8 * i];      // 0 for OOB rows
      av4.x += wv * xr[i].x; av4.y += wv * xr[i].y;
      av4.z += wv * xr[i].z; av4.w += wv * xr[i].w;
    }
    // no barrier needed: next stage only touches xb/regs; w_lds rewritten after next sync2
  }

  // ---- merge the 8 row-block partials per column (reuse pbuf as [3][8][136]) ----
  float* mb = pbuf;
  {
    const int base = rb * 136 + c4;
    *(float4*)(&mb[       base]) = sum4;
    *(float4*)(&mb[1088 + base]) = mx4;
    *(float4*)(&mb[2176 + base]) = av4;
  }
  __syncthreads();
  if (tid < H) {
    const int c = tid;
    float sv = 0.f, mv = -INFINITY, av = 0.f;
#pragma unroll
    for (int r8 = 0; r8 < 8; ++r8) {
      sv += mb[r8 * 136 + c];
      mv  = fmaxf(mv, mb[1088 + r8 * 136 + c]);
      av += mb[2176 + r8 * 136 + c];
    }
    float* og = out + (size_t)g * (3 * H);
    og[c]         = sv / fmaxf((float)R, 1.0f);
    og[H + c]     = mv;                              // -inf for empty segment
    og[2 * H + c] = (R > 0) ? (av / l_run) : 0.0f;   // l_run >= 1 when R > 0
  }
}

extern "C" void kernel_launch(void* const* d_in, const int* in_sizes, int n_in,
                              void* d_out, int out_size, void* d_ws, size_t ws_size,
                              hipStream_t stream)
{
  const float* x   = (const float*)d_in[0];
  const float* w1  = (const float*)d_in[1];
  const float* b1  = (const float*)d_in[2];
  const float* w2  = (const float*)d_in[3];
  const float* b2  = (const float*)d_in[4];
  const int*  bidx = (const int*)d_in[5];

  const int N  = in_sizes[5];            // batch_index length
  const int Bn = out_size / (3 * H);     // num graphs

  // workspace: seg_start then w1t
  char* ws = (char*)d_ws;
  size_t off = 0;
  int* seg_start = (int*)(ws + off);
  off += (size_t)(Bn + 1) * sizeof(int);
  off = (off + 255) & ~(size_t)255;
  short* w1t = (short*)(ws + off);

  prep_kernel<<<(H * H + 255) / 256, 256, 0, stream>>>(w1, w1t);
  bounds_kernel<<<(N + 255) / 256, 256, 0, stream>>>(bidx, seg_start, N, Bn);
  fused_kernel<<<Bn, 256, 0, stream>>>(x, w1t, b1, w2, b2, seg_start, (float*)d_out);
}

// Round 2
// 930.273 us; speedup vs baseline: 1.1096x; 1.1096x over previous
//
#include <hip/hip_runtime.h>
#include <hip/hip_bf16.h>
#include <math.h>

#define H 128
#define TILE 64
#define XB_STRIDE 136   // bf16 elems per LDS row: 272B -> 2-way bank aliasing (free)
#define PB_STRIDE 68    // f32 elems per pbuf row: 272B

typedef __attribute__((ext_vector_type(8))) short bf16x8;
typedef __attribute__((ext_vector_type(4))) float f32x4;

__device__ __forceinline__ short f2bf(float f) {
  union { float f; unsigned u; } v; v.f = f;
  unsigned r = v.u + 0x7fffu + ((v.u >> 16) & 1u);  // round-to-nearest-even
  return (short)(r >> 16);
}

// ---- K0: W1 (fp32, [k][n]) -> W1T bf16 [n][k], so B-frags are contiguous 16B ----
__global__ void prep_kernel(const float* __restrict__ w1, short* __restrict__ w1t) {
  int i = blockIdx.x * blockDim.x + threadIdx.x;   // 0 .. H*H-1
  if (i >= H * H) return;
  int k = i >> 7, n = i & (H - 1);
  w1t[n * H + k] = f2bf(w1[k * H + n]);
}

// ---- K1: segment boundaries from sorted batch_index ----
__global__ void bounds_kernel(const int* __restrict__ bi, int* __restrict__ seg_start,
                              int N, int B) {
  int n = blockIdx.x * blockDim.x + threadIdx.x;
  if (n >= N) return;
  int cur = bi[n];
  int prev = (n == 0) ? -1 : bi[n - 1];
  for (int g = prev + 1; g <= cur; ++g) seg_start[g] = n;
  if (n == N - 1) {
    for (int g = cur + 1; g <= B; ++g) seg_start[g] = N;
  }
}

// ---- K2: fused per-graph readout. Softmax weights once per row; pool pass
//      re-reads x from global (L2-hot, zero registers held across barriers). ----
__global__ __launch_bounds__(256) void fused_kernel(
    const float* __restrict__ x, const short* __restrict__ w1t,
    const float* __restrict__ b1, const float* __restrict__ w2,
    const float* __restrict__ b2, const int* __restrict__ seg_start,
    float* __restrict__ out)
{
  __shared__ __align__(16) short xb[TILE * XB_STRIDE];    // 17.4 KB bf16 tile (MFMA A)
  __shared__ __align__(16) float pbuf[TILE * PB_STRIDE];  // 17.4 KB gate partials; reused as merge buf
  __shared__ float w_lds[TILE];                           // per-row softmax weights
  __shared__ float bc2[2];                                // {m_new, tile_l} broadcast

  const int g = blockIdx.x;
  const int s = seg_start[g];
  const int e = seg_start[g + 1];
  const int R = e - s;

  const int tid  = threadIdx.x;
  const int w    = tid >> 6;       // wave 0..3 -> cols [32w, 32w+32)
  const int lane = tid & 63;
  const int l15  = lane & 15;
  const int q    = lane >> 4;

  // staging/pool identity: cols [c4, c4+4), rows rb + 8i
  const int c4 = (tid & 31) * 4;
  const int rb = tid >> 5;

  float4 sum4 = make_float4(0.f, 0.f, 0.f, 0.f);
  float4 mx4  = make_float4(-INFINITY, -INFINITY, -INFINITY, -INFINITY);
  float4 av4  = make_float4(0.f, 0.f, 0.f, 0.f);
  float m_run = -INFINITY, l_run = 0.f;

  const float b2v  = b2[0];
  const int   c0   = 32 * w + l15, c1 = c0 + 16;
  const float w2c0 = w2[c0], w2c1 = w2[c1];
  const float b1c0 = b1[c0], b1c1 = b1[c1];

  for (int t0 = 0; t0 < R; t0 += TILE) {
    const int Rt    = min(TILE, R - t0);
    const int mtMax = (Rt + 15) >> 4;    // skip all-OOB M-subtiles on tail tiles

    // ---- stage: global fp32 -> LDS bf16 only (no register retention) ----
#pragma unroll
    for (int i = 0; i < 8; ++i) {
      const int row = rb + 8 * i;
      float4 v = make_float4(0.f, 0.f, 0.f, 0.f);
      if (row < Rt) v = *(const float4*)(x + (size_t)(s + t0 + row) * H + c4);
      short4 sv = make_short4(f2bf(v.x), f2bf(v.y), f2bf(v.z), f2bf(v.w));
      *(short4*)(&xb[row * XB_STRIDE + c4]) = sv;   // zeros for OOB rows (clean A-frags)
    }
    __syncthreads();   // sync1: xb ready

    // ---- gate GEMM: (up to) 64x128 @ 128x128, bf16 MFMA ----
    f32x4 acc[4][2] = {};
#pragma unroll
    for (int kc = 0; kc < H; kc += 32) {
      bf16x8 a[4], b[2];
#pragma unroll
      for (int mt = 0; mt < 4; ++mt)
        if (mt < mtMax)
          a[mt] = *(const bf16x8*)(&xb[(16 * mt + l15) * XB_STRIDE + kc + 8 * q]);
#pragma unroll
      for (int nt = 0; nt < 2; ++nt) {
        int n = 32 * w + 16 * nt + l15;
        b[nt] = *(const bf16x8*)(w1t + n * H + kc + 8 * q);
      }
#pragma unroll
      for (int mt = 0; mt < 4; ++mt)
        if (mt < mtMax)
#pragma unroll
          for (int nt = 0; nt < 2; ++nt)
            acc[mt][nt] = __builtin_amdgcn_mfma_f32_16x16x32_bf16(a[mt], b[nt], acc[mt][nt], 0, 0, 0);
    }

    // ---- epilogue: silu(h)*W2 per (row, col-pair) -> pbuf[row][slot], no shfl/atomics ----
#pragma unroll
    for (int mt = 0; mt < 4; ++mt) {
      if (mt < mtMax) {
#pragma unroll
        for (int r = 0; r < 4; ++r) {
          float h0 = acc[mt][0][r] + b1c0;
          float h1 = acc[mt][1][r] + b1c1;
          float s0 = h0 / (1.0f + __expf(-h0));
          float s1 = h1 / (1.0f + __expf(-h1));
          pbuf[(16 * mt + 4 * q + r) * PB_STRIDE + 16 * w + l15] = s0 * w2c0 + s1 * w2c1;
        }
      }
    }
    __syncthreads();   // sync2: pbuf ready

    // ---- wave0: per-row gate, tile max, per-row exp weights, tile denom ----
    if (tid < 64) {
      const int row = tid;
      float4 t4 = make_float4(0.f, 0.f, 0.f, 0.f);
#pragma unroll
      for (int j = 0; j < 16; ++j) {
        float4 pv = *(const float4*)(&pbuf[row * PB_STRIDE + 4 * j]);
        t4.x += pv.x; t4.y += pv.y; t4.z += pv.z; t4.w += pv.w;
      }
      const float gate = (t4.x + t4.y) + (t4.z + t4.w) + b2v;
      const bool valid = row < Rt;
      float gm = valid ? gate : -INFINITY;    // mask stale/garbage rows
#pragma unroll
      for (int m = 1; m < 64; m <<= 1) gm = fmaxf(gm, __shfl_xor(gm, m));
      const float m_new = fmaxf(m_run, gm);   // m_run identical on every thread
      const float wv = valid ? __expf(gate - m_new) : 0.f;
      w_lds[row] = wv;
      float tl = wv;
#pragma unroll
      for (int m = 1; m < 64; m <<= 1) tl += __shfl_xor(tl, m);
      if (tid == 0) { bc2[0] = m_new; bc2[1] = tl; }
    }
    __syncthreads();   // sync3: w_lds/bc2 ready

    // ---- pool pass: re-read x (L2-hot), fold sum/max/attn in one load ----
    const float m_new = bc2[0];
    const float tl    = bc2[1];
    const float corr  = __expf(m_run - m_new);   // first tile: exp(-inf)=0
    m_run = m_new;
    l_run = l_run * corr + tl;
    av4.x *= corr; av4.y *= corr; av4.z *= corr; av4.w *= corr;
#pragma unroll
    for (int i = 0; i < 8; ++i) {
      const int row = rb + 8 * i;
      if (row < Rt) {
        const float4 v = *(const float4*)(x + (size_t)(s + t0 + row) * H + c4);
        const float wv = w_lds[row];
        sum4.x += v.x; sum4.y += v.y; sum4.z += v.z; sum4.w += v.w;
        mx4.x = fmaxf(mx4.x, v.x); mx4.y = fmaxf(mx4.y, v.y);
        mx4.z = fmaxf(mx4.z, v.z); mx4.w = fmaxf(mx4.w, v.w);
        av4.x += wv * v.x; av4.y += wv * v.y;
        av4.z += wv * v.z; av4.w += wv * v.w;
      }
    }
    // no barrier needed: next stage only touches xb; w_lds rewritten after next sync2,
    // which every thread reaches only after finishing this pool pass (sync1 ordering)
  }

  // ---- merge the 8 row-block partials per column (reuse pbuf as [3][8][136]) ----
  float* mb = pbuf;
  {
    const int base = rb * 136 + c4;
    *(float4*)(&mb[       base]) = sum4;
    *(float4*)(&mb[1088 + base]) = mx4;
    *(float4*)(&mb[2176 + base]) = av4;
  }
  __syncthreads();
  if (tid < H) {
    const int c = tid;
    float sv = 0.f, mv = -INFINITY, av = 0.f;
#pragma unroll
    for (int r8 = 0; r8 < 8; ++r8) {
      sv += mb[r8 * 136 + c];
      mv  = fmaxf(mv, mb[1088 + r8 * 136 + c]);
      av += mb[2176 + r8 * 136 + c];
    }
    float* og = out + (size_t)g * (3 * H);
    og[c]         = sv / fmaxf((float)R, 1.0f);
    og[H + c]     = mv;                              // -inf for empty segment
    og[2 * H + c] = (R > 0) ? (av / l_run) : 0.0f;   // l_run >= 1 when R > 0
  }
}

extern "C" void kernel_launch(void* const* d_in, const int* in_sizes, int n_in,
                              void* d_out, int out_size, void* d_ws, size_t ws_size,
                              hipStream_t stream)
{
  const float* x   = (const float*)d_in[0];
  const float* w1  = (const float*)d_in[1];
  const float* b1  = (const float*)d_in[2];
  const float* w2  = (const float*)d_in[3];
  const float* b2  = (const float*)d_in[4];
  const int*  bidx = (const int*)d_in[5];

  const int N  = in_sizes[5];            // batch_index length
  const int Bn = out_size / (3 * H);     // num graphs

  // workspace: seg_start then w1t
  char* ws = (char*)d_ws;
  size_t off = 0;
  int* seg_start = (int*)(ws + off);
  off += (size_t)(Bn + 1) * sizeof(int);
  off = (off + 255) & ~(size_t)255;
  short* w1t = (short*)(ws + off);

  prep_kernel<<<(H * H + 255) / 256, 256, 0, stream>>>(w1, w1t);
  bounds_kernel<<<(N + 255) / 256, 256, 0, stream>>>(bidx, seg_start, N, Bn);
  fused_kernel<<<Bn, 256, 0, stream>>>(x, w1t, b1, w2, b2, seg_start, (float*)d_out);
}